// Round 5
// baseline (9078.113 us; speedup 1.0000x reference)
//
#include <hip/hip_runtime.h>
#include <cmath>

// ---------------------------------------------------------------------------
// QRNN decoder, MI355X. B=32 T=64 S=128 EMB=H=E=512 V=32000 K=2.
// f32-faithful pipeline (sharp softmax -> argmax flips if any fp16 error
// reaches the score path). Split-fp16 (hi+lo) 3-term MFMA GEMMs for gates
// and EP = enc @ kpW^T; decode recurrence fully f32; vocab GEMM plain fp16.
// Decode: cooperative kernel, 8 blocks per batch, enc/EP slices LDS-resident,
// per-b device-scope barriers (2 per step). Fallback to 32-block version if
// cooperative launch is unavailable.
// ---------------------------------------------------------------------------

typedef _Float16 half8  __attribute__((ext_vector_type(8)));
typedef float    f32x4  __attribute__((ext_vector_type(4)));

#define DEVFN static __device__ __forceinline__

DEVFN float sigp(float x){ return 1.f/(1.f+expf(-x)); }

DEVFN void glds16(const _Float16* g, _Float16* l){
  __builtin_amdgcn_global_load_lds((const __attribute__((address_space(1))) void*)g,
                                   (__attribute__((address_space(3))) void*)l, 16, 0, 0);
}

// ---------------- encoder-hidden projections: 5 x (B,E)@(E,H), f32 ---------
__global__ void ep_proj(const float* __restrict__ ehid,
    const float* __restrict__ w0, const float* __restrict__ b0,
    const float* __restrict__ w1, const float* __restrict__ b1,
    const float* __restrict__ w2, const float* __restrict__ b2,
    const float* __restrict__ w3, const float* __restrict__ b3,
    const float* __restrict__ w4, const float* __restrict__ b4,
    float* __restrict__ ep)
{
  int gid = blockIdx.x*256 + threadIdx.x;            // 5*32*512*4 = 327680
  int q = gid & 3, h = (gid>>2)&511, b = (gid>>11)&31, p = gid>>16;
  const float* w    = (p==0)?w0:(p==1)?w1:(p==2)?w2:(p==3)?w3:w4;
  const float* bias = (p==0)?b0:(p==1)?b1:(p==2)?b2:(p==3)?b3:b4;
  const float* x  = ehid + ((p>=3)?32*512:0) + b*512 + q*128;
  const float* wr = w + (size_t)h*512 + q*128;
  float acc = 0.f;
  #pragma unroll 8
  for (int j=0;j<128;j+=4){
    float4 wv = *(const float4*)(wr+j);
    float4 xv = *(const float4*)(x+j);
    acc += wv.x*xv.x + wv.y*xv.y + wv.z*xv.z + wv.w*xv.w;
  }
  acc += __shfl_xor(acc,1); acc += __shfl_xor(acc,2);
  if (q==0) ep[p*16384 + b*512 + h] = acc + bias[h];
}

// ---------------- hi/lo fp16 packing ---------------------------------------
__global__ void pack2(const float* __restrict__ trg,
  const float* __restrict__ zW0, const float* __restrict__ fW0,
  const float* __restrict__ oW0, const float* __restrict__ iW0,
  const float* __restrict__ zW1, const float* __restrict__ fW1,
  const float* __restrict__ oW1,
  const float* __restrict__ enc, const float* __restrict__ kpW,
  _Float16* __restrict__ A0h, _Float16* __restrict__ A0l,
  _Float16* __restrict__ W0h, _Float16* __restrict__ W0l,
  _Float16* __restrict__ W1h, _Float16* __restrict__ W1l,
  _Float16* __restrict__ ench, _Float16* __restrict__ encl,
  _Float16* __restrict__ kph, _Float16* __restrict__ kpl)
{
  int gid = blockIdx.x*256 + threadIdx.x;            // 8,126,464 total
  float v; _Float16 *ph, *pl; int idx;
  if (gid < 2097152) {
    idx = gid;
    int m = idx >> 10, c = idx & 1023, t = m & 63, kk = c >> 9, i = c & 511;
    v = (kk==0) ? ((t>0) ? trg[(size_t)(m-1)*512 + i] : 0.f)
                : trg[(size_t)m*512 + i];
    ph = A0h; pl = A0l;
  } else if (gid < 4194304) {
    idx = gid - 2097152;
    int r = idx >> 10, c = idx & 1023, g = r >> 9, o = r & 511, kk = c >> 9, i = c & 511;
    const float* W = (g==0)?zW0:(g==1)?fW0:(g==2)?oW0:iW0;
    v = W[(size_t)o*1024 + i*2 + kk];
    ph = W0h; pl = W0l;
  } else if (gid < 5767168) {
    idx = gid - 4194304;
    int r = idx >> 10, c = idx & 1023, g = r >> 9, o = r & 511, kk = c >> 9, i = c & 511;
    const float* W = (g==0)?zW1:(g==1)?fW1:oW1;
    v = W[(size_t)o*1024 + i*2 + kk];
    ph = W1h; pl = W1l;
  } else if (gid < 7864320) {
    idx = gid - 5767168;
    v = enc[idx];
    ph = ench; pl = encl;
  } else {
    idx = gid - 7864320;
    v = kpW[idx];
    ph = kph; pl = kpl;
  }
  _Float16 hi = (_Float16)v;
  _Float16 lo = (_Float16)(v - (float)hi);
  ph[idx] = hi; pl[idx] = lo;
}

// ---------------- split-fp16 3-term MFMA GEMM ------------------------------
__global__ __launch_bounds__(256) void gemm3(
    const _Float16* __restrict__ Ah, const _Float16* __restrict__ Al,
    const _Float16* __restrict__ Bh, const _Float16* __restrict__ Bl,
    float* __restrict__ C, int Kd, int ldc)
{
  __shared__ __align__(16) _Float16 Ahs[4096];
  __shared__ __align__(16) _Float16 Als[4096];
  __shared__ __align__(16) _Float16 Bhs[4096];
  __shared__ __align__(16) _Float16 Bls[4096];
  const int tid = threadIdx.x, lane = tid & 63, wave = tid >> 6;
  const int bm = blockIdx.x, bn = blockIdx.y;
  const int wm = wave >> 1, wn = wave & 1;
  const size_t aoff = ((size_t)bm*128 + wave*16 + (lane>>2))*Kd + (lane&3)*8;
  const size_t boff = ((size_t)bn*128 + wave*16 + (lane>>2))*Kd + (lane&3)*8;
  const size_t hstep = (size_t)64*Kd;
  _Float16* Ahl = Ahs + wave*512;
  _Float16* All = Als + wave*512;
  _Float16* Bhl = Bhs + wave*512;
  _Float16* Bll = Bls + wave*512;
  f32x4 acc[4][4] = {};
  for (int k0 = 0; k0 < Kd; k0 += 32) {
    glds16(Ah + aoff + k0, Ahl);  glds16(Ah + aoff + hstep + k0, Ahl + 2048);
    glds16(Al + aoff + k0, All);  glds16(Al + aoff + hstep + k0, All + 2048);
    glds16(Bh + boff + k0, Bhl);  glds16(Bh + boff + hstep + k0, Bhl + 2048);
    glds16(Bl + boff + k0, Bll);  glds16(Bl + boff + hstep + k0, Bll + 2048);
    __syncthreads();
    const int ar = lane & 15, kb = (lane>>4)*8;
    half8 ah[4], al[4], bh[4], bl[4];
    #pragma unroll
    for (int m=0;m<4;++m){
      ah[m] = *(const half8*)&Ahs[(wm*64 + m*16 + ar)*32 + kb];
      al[m] = *(const half8*)&Als[(wm*64 + m*16 + ar)*32 + kb];
    }
    #pragma unroll
    for (int n=0;n<4;++n){
      bh[n] = *(const half8*)&Bhs[(wn*64 + n*16 + ar)*32 + kb];
      bl[n] = *(const half8*)&Bls[(wn*64 + n*16 + ar)*32 + kb];
    }
    #pragma unroll
    for (int m=0;m<4;++m)
      #pragma unroll
      for (int n=0;n<4;++n){
        acc[m][n] = __builtin_amdgcn_mfma_f32_16x16x32_f16(ah[m], bh[n], acc[m][n], 0,0,0);
        acc[m][n] = __builtin_amdgcn_mfma_f32_16x16x32_f16(ah[m], bl[n], acc[m][n], 0,0,0);
        acc[m][n] = __builtin_amdgcn_mfma_f32_16x16x32_f16(al[m], bh[n], acc[m][n], 0,0,0);
      }
    __syncthreads();
  }
  const int r0 = bm*128 + wm*64 + ((lane>>4)<<2);
  const int c0 = bn*128 + wn*64 + (lane&15);
  #pragma unroll
  for (int m=0;m<4;++m)
    #pragma unroll
    for (int n=0;n<4;++n)
      #pragma unroll
      for (int e=0;e<4;++e)
        C[(size_t)(r0 + m*16 + e)*ldc + c0 + n*16] = acc[m][n][e];
}

// ---------------- vocab GEMM: plain fp16 A x f32->fp16 B -------------------
__global__ __launch_bounds__(256) void gemm_hf(
    const _Float16* __restrict__ A, const float* __restrict__ Bf,
    float* __restrict__ C, int Kd, int ldc)
{
  __shared__ __align__(16) _Float16 As[128*32];
  __shared__ __align__(16) _Float16 Bs[128*32];
  const int tid = threadIdx.x, lane = tid & 63, wave = tid >> 6;
  const int bm = blockIdx.x, bn = blockIdx.y;
  const int wm = wave >> 1, wn = wave & 1;
  const _Float16* Ag = A + ((size_t)bm*128 + wave*16 + (lane>>2))*Kd + (lane&3)*8;
  _Float16* Al = As + wave*512;
  const float* Bg = Bf + ((size_t)bn*128 + (tid>>2))*Kd + (tid&3)*8;
  f32x4 acc[4][4] = {};
  for (int k0 = 0; k0 < Kd; k0 += 32) {
    glds16(Ag + k0, Al);
    glds16(Ag + (size_t)64*Kd + k0, Al + 2048);
    #pragma unroll
    for (int i=0;i<2;++i){
      const float* src = Bg + (size_t)i*64*Kd + k0;
      float4 f0 = *(const float4*)src;
      float4 f1 = *(const float4*)(src+4);
      half8 hv = {(_Float16)f0.x,(_Float16)f0.y,(_Float16)f0.z,(_Float16)f0.w,
                  (_Float16)f1.x,(_Float16)f1.y,(_Float16)f1.z,(_Float16)f1.w};
      *(half8*)&Bs[i*2048 + tid*8] = hv;
    }
    __syncthreads();
    half8 af[4], bf[4];
    const int ar = lane & 15, kb = (lane>>4)*8;
    #pragma unroll
    for (int m=0;m<4;++m) af[m] = *(const half8*)&As[(wm*64 + m*16 + ar)*32 + kb];
    #pragma unroll
    for (int n=0;n<4;++n) bf[n] = *(const half8*)&Bs[(wn*64 + n*16 + ar)*32 + kb];
    #pragma unroll
    for (int m=0;m<4;++m)
      #pragma unroll
      for (int n=0;n<4;++n)
        acc[m][n] = __builtin_amdgcn_mfma_f32_16x16x32_f16(af[m], bf[n], acc[m][n], 0,0,0);
    __syncthreads();
  }
  const int r0 = bm*128 + wm*64 + ((lane>>4)<<2);
  const int c0 = bn*128 + wn*64 + (lane&15);
  #pragma unroll
  for (int m=0;m<4;++m)
    #pragma unroll
    for (int n=0;n<4;++n)
      #pragma unroll
      for (int e=0;e<4;++e)
        C[(size_t)(r0 + m*16 + e)*ldc + c0 + n*16] = acc[m][n][e];
}

// ---------------- layer-0 scan: f32, writes A1 hi/lo -----------------------
__global__ void scan0(const float* __restrict__ C0, const float* __restrict__ ep,
    const float* __restrict__ zb0, const float* __restrict__ fb0,
    const float* __restrict__ ob0, const float* __restrict__ ib0,
    _Float16* __restrict__ A1h, _Float16* __restrict__ A1l)
{
  int gid = blockIdx.x*256 + threadIdx.x;   // 16384
  int h = gid & 511, b = gid >> 9;
  float ez = ep[b*512 + h];
  float eo = ep[16384 + b*512 + h];
  float ei = ep[32768 + b*512 + h];
  float bz = zb0[h], bff = fb0[h], bo = ob0[h], bi = ib0[h];
  float c = 0.f;
  size_t base = (size_t)b*64*1024;
  A1h[base + h] = (_Float16)0.f;
  A1l[base + h] = (_Float16)0.f;
  for (int t=0;t<64;++t){
    size_t row = (size_t)b*64 + t;
    const float* g = C0 + row*2048;
    float z = tanhf(g[h]      + bz  + ez);
    float f = sigp (g[512+h]  + bff + ez);   // f0 uses epz0 (per reference)
    float o = sigp (g[1024+h] + bo  + eo);
    float i = sigp (g[1536+h] + bi  + ei);
    c = f*c + i*z;
    float h0 = o*c;
    _Float16 hi = (_Float16)h0;
    _Float16 lo = (_Float16)(h0 - (float)hi);
    A1h[row*1024 + 512 + h] = hi;
    A1l[row*1024 + 512 + h] = lo;
    if (t < 63){
      A1h[(row+1)*1024 + h] = hi;
      A1l[(row+1)*1024 + h] = lo;
    }
  }
}

// ---------------- layer-1 activations: F1, O1, PZ=(1-f1)*z1 ----------------
__global__ void act1(const float* __restrict__ C1, const float* __restrict__ ep,
    const float* __restrict__ zb1, const float* __restrict__ fb1,
    const float* __restrict__ ob1,
    float* __restrict__ F1, float* __restrict__ O1, float* __restrict__ PZ)
{
  int gid = blockIdx.x*256 + threadIdx.x;   // 2048*512
  int h = gid & 511; size_t row = gid >> 9; int b = (int)(row >> 6);
  const float* g = C1 + row*1536;
  float ez = ep[3*16384 + b*512 + h];
  float eo = ep[4*16384 + b*512 + h];
  float z1 = tanhf(g[h]      + zb1[h] + ez);
  float f1 = sigp (g[512+h]  + fb1[h] + ez);   // f1 uses epz1 (per reference)
  float o1 = sigp (g[1024+h] + ob1[h] + eo);
  F1[gid] = f1; O1[gid] = o1; PZ[gid] = (1.f - f1)*z1;
}

// ---------------- per-b device barrier (monotonic counter) -----------------
DEVFN void bbar(int* cnt, int target){
  __threadfence();
  __syncthreads();
  if (threadIdx.x == 0) {
    __hip_atomic_fetch_add(cnt, 1, __ATOMIC_ACQ_REL, __HIP_MEMORY_SCOPE_AGENT);
    while (__hip_atomic_load(cnt, __ATOMIC_ACQUIRE, __HIP_MEMORY_SCOPE_AGENT) < target)
      __builtin_amdgcn_s_sleep(4);
  }
  __syncthreads();
  __threadfence();
}

__global__ void zinit(int* cnt){ cnt[threadIdx.x] = 0; }

// ---------------- cooperative decode: 256 blocks (8 per b) -----------------
// block j: b = j&31, w = j>>5 (same-XCD grouping per b under round-robin).
// LDS-resident: enc s-rows [w*16,+16), enc h-cols [w*64,+64), EP h-cols.
// Per step: 2 per-b barriers (c1n exchange, scores exchange).
__global__ __launch_bounds__(512,1) void decode_coop(
  const float* __restrict__ enc, const float* __restrict__ F1,
  const float* __restrict__ O1, const float* __restrict__ PZ,
  const float* __restrict__ EP, const float* __restrict__ cpW,
  const float* __restrict__ kpb, const float* __restrict__ cpb,
  float* __restrict__ att_probs, float* __restrict__ att_vec,
  _Float16* __restrict__ A2,
  float* __restrict__ c1g, float* __restrict__ sg, int* __restrict__ cnt)
{
  __shared__ __align__(16) float encS[16*512];   // 32 KB
  __shared__ __align__(16) float encC[128*64];   // 32 KB
  __shared__ __align__(16) float epC [128*64];   // 32 KB
  __shared__ __align__(16) float c1full[512];
  __shared__ float alpha[128];
  __shared__ float kpart[8][64];
  __shared__ float kppart[8][64];
  __shared__ float h1s[64], o1s[64], bs[64], kps[64];
  __shared__ float red[8];
  const int j = blockIdx.x, b = j & 31, w = j >> 5;
  const int tid = threadIdx.x;
  const float* encb = enc + (size_t)b*65536;
  const float* EPb  = EP  + (size_t)b*65536;
  int* mycnt = cnt + b*16;

  // static preloads (once)
  for (int i = tid; i < 2048; i += 512)
    ((float4*)encS)[i] = *(const float4*)(encb + (size_t)(w*16 + (i>>7))*512 + ((i&127)<<2));
  for (int i = tid; i < 2048; i += 512) {
    int s = i >> 4, c4 = (i & 15) << 2;
    ((float4*)encC)[i] = *(const float4*)(encb + (size_t)s*512 + w*64 + c4);
    ((float4*)epC )[i] = *(const float4*)(EPb  + (size_t)s*512 + w*64 + c4);
  }
  if (tid < 64) {
    h1s[tid] = 0.f;
    bs[tid] = kpb[w*64+tid] + cpb[w*64+tid];
  }
  __syncthreads();

  int barn = 0;
  for (int t = 0; t < 64; ++t) {
    const size_t bt = (size_t)b*64 + t;
    // phase 1: c1n slice (local state), publish to c1g
    if (tid < 64) {
      int h = w*64 + tid;
      float f1 = F1[bt*512 + h];
      float pz = PZ[bt*512 + h];
      float c1 = f1*h1s[tid] + pz;
      o1s[tid] = O1[bt*512 + h];
      c1g[b*512 + h] = c1;
    }
    bbar(mycnt, 8*(++barn));                    // barrier 1
    // phase 2: gather full c1n
    c1full[tid] = c1g[b*512 + tid];
    __syncthreads();
    // phase 3: scores for 16 s-rows (from LDS)
    {
      int s = tid >> 5, q = tid & 31;
      const float* er = encS + s*512;
      float acc = 0.f;
      #pragma unroll
      for (int jj = 0; jj < 4; ++jj) {
        int col = q*4 + jj*128;
        float4 e = *(const float4*)(er + col);
        float4 c = *(const float4*)(c1full + col);
        acc += e.x*c.x + e.y*c.y + e.z*c.z + e.w*c.w;
      }
      acc += __shfl_xor(acc,1);  acc += __shfl_xor(acc,2);
      acc += __shfl_xor(acc,4);  acc += __shfl_xor(acc,8);
      acc += __shfl_xor(acc,16);
      if (q == 0) sg[b*128 + w*16 + s] = acc;
    }
    bbar(mycnt, 8*(++barn));                    // barrier 2
    // phase 4: softmax (redundant per block)
    {
      int wid = tid >> 6;
      float sv = 0.f, e = 0.f;
      if (tid < 128) {
        sv = sg[b*128 + tid];
        float m = sv;
        #pragma unroll
        for (int off=32; off; off>>=1) m = fmaxf(m, __shfl_xor(m, off));
        if ((tid & 63) == 0) red[wid] = m;
      }
      __syncthreads();
      float m = fmaxf(red[0], red[1]);
      if (tid < 128) {
        e = expf(sv - m);
        float s2 = e;
        #pragma unroll
        for (int off=32; off; off>>=1) s2 += __shfl_xor(s2, off);
        if ((tid & 63) == 0) red[4+wid] = s2;
      }
      __syncthreads();
      if (tid < 128) alpha[tid] = e * (1.f/(red[4]+red[5]));
      __syncthreads();
      if (tid < 16) att_probs[bt*128 + w*16 + tid] = alpha[w*16 + tid];
    }
    // phase 5: k, kp for h-slice (from LDS cols)
    {
      int hh = tid & 63, g = tid >> 6;
      float kv = 0.f, pv = 0.f;
      #pragma unroll
      for (int si = 0; si < 16; ++si) {
        float a = alpha[g*16 + si];
        kv += a * encC[(g*16+si)*64 + hh];
        pv += a * epC [(g*16+si)*64 + hh];
      }
      kpart[g][hh] = kv; kppart[g][hh] = pv;
    }
    __syncthreads();
    if (tid < 64) {
      float kv = 0.f, pv = 0.f;
      #pragma unroll
      for (int g = 0; g < 8; ++g){ kv += kpart[g][tid]; pv += kppart[g][tid]; }
      att_vec[bt*512 + w*64 + tid] = kv;
      kps[tid] = pv;
    }
    __syncthreads();
    // phase 6: h1n slice = (kp + c1n.cpW[h,:] + bias)*o1 ; cpW rows from L2
    {
      int hh = tid >> 3, q = tid & 7;
      float4 c1r[16];
      #pragma unroll
      for (int jj = 0; jj < 16; ++jj) c1r[jj] = *(const float4*)(c1full + jj*32 + q*4);
      const float* wr = cpW + (size_t)(w*64 + hh)*512;
      float acc = 0.f;
      #pragma unroll
      for (int jj = 0; jj < 16; ++jj) {
        float4 w4 = *(const float4*)(wr + jj*32 + q*4);
        acc += w4.x*c1r[jj].x + w4.y*c1r[jj].y + w4.z*c1r[jj].z + w4.w*c1r[jj].w;
      }
      acc += __shfl_xor(acc,1); acc += __shfl_xor(acc,2); acc += __shfl_xor(acc,4);
      if (q == 0) {
        float h1n = (acc + kps[hh] + bs[hh]) * o1s[hh];
        h1s[hh] = h1n;
        A2[bt*512 + w*64 + hh] = (_Float16)h1n;
      }
    }
    __syncthreads();
  }
}

// ---------------- fallback decode (round-4, 32 blocks) ---------------------
__global__ __launch_bounds__(512,1) void decode(
  const float* __restrict__ enc, const float* __restrict__ F1,
  const float* __restrict__ O1, const float* __restrict__ PZ,
  const float* __restrict__ EP, const float* __restrict__ cpW,
  const float* __restrict__ kpb, const float* __restrict__ cpb,
  float* __restrict__ att_probs, float* __restrict__ att_vec,
  _Float16* __restrict__ A2)
{
  __shared__ float c1s[512], h1s[512], bsum[512], kps[512];
  __shared__ float scores[128], alpha[128];
  __shared__ float kq[8][512], kpq[8][512];
  const int b = blockIdx.x, tid = threadIdx.x;
  const float* encb = enc + (size_t)b*65536;
  const float* EPb  = EP  + (size_t)b*65536;
  h1s[tid] = 0.f;
  bsum[tid] = kpb[tid] + cpb[tid];
  __syncthreads();
  for (int t = 0; t < 64; ++t) {
    const size_t bt = (size_t)b*64 + t;
    c1s[tid] = F1[bt*512 + tid]*h1s[tid] + PZ[bt*512 + tid];
    __syncthreads();
    {
      int s = tid >> 2, q = tid & 3;
      const float* er = encb + s*512 + q*128;
      const float* cr = c1s + q*128;
      float acc = 0.f;
      #pragma unroll
      for (int j = 0; j < 32; ++j) {
        float4 e = *(const float4*)(er + j*4);
        float4 c = *(const float4*)(cr + j*4);
        acc += e.x*c.x + e.y*c.y + e.z*c.z + e.w*c.w;
      }
      acc += __shfl_xor(acc,1);
      acc += __shfl_xor(acc,2);
      if (q == 0) scores[s] = acc;
    }
    __syncthreads();
    if (tid < 64) {
      float s0 = scores[tid], s1 = scores[tid+64];
      float m = fmaxf(s0, s1);
      #pragma unroll
      for (int off=32; off; off>>=1) m = fmaxf(m, __shfl_xor(m, off));
      float e0 = expf(s0-m), e1 = expf(s1-m);
      float sm = e0+e1;
      #pragma unroll
      for (int off=32; off; off>>=1) sm += __shfl_xor(sm, off);
      float inv = 1.f/sm;
      alpha[tid] = e0*inv; alpha[tid+64] = e1*inv;
      att_probs[bt*128 + tid] = e0*inv; att_probs[bt*128 + 64 + tid] = e1*inv;
    }
    __syncthreads();
    {
      int w = tid >> 6, l = tid & 63;
      const float* er = encb + (size_t)(w*16)*512 + l*8;
      const float* pr = EPb  + (size_t)(w*16)*512 + l*8;
      float k0=0,k1=0,k2=0,k3=0,k4=0,k5=0,k6=0,k7=0;
      float p0=0,p1=0,p2=0,p3=0,p4=0,p5=0,p6=0,p7=0;
      #pragma unroll
      for (int si = 0; si < 16; ++si) {
        float a = alpha[w*16 + si];
        float4 e0 = *(const float4*)(er + si*512);
        float4 e1 = *(const float4*)(er + si*512 + 4);
        float4 q0 = *(const float4*)(pr + si*512);
        float4 q1 = *(const float4*)(pr + si*512 + 4);
        k0 += a*e0.x; k1 += a*e0.y; k2 += a*e0.z; k3 += a*e0.w;
        k4 += a*e1.x; k5 += a*e1.y; k6 += a*e1.z; k7 += a*e1.w;
        p0 += a*q0.x; p1 += a*q0.y; p2 += a*q0.z; p3 += a*q0.w;
        p4 += a*q1.x; p5 += a*q1.y; p6 += a*q1.z; p7 += a*q1.w;
      }
      *(float4*)&kq[w][l*8]    = make_float4(k0,k1,k2,k3);
      *(float4*)&kq[w][l*8+4]  = make_float4(k4,k5,k6,k7);
      *(float4*)&kpq[w][l*8]   = make_float4(p0,p1,p2,p3);
      *(float4*)&kpq[w][l*8+4] = make_float4(p4,p5,p6,p7);
    }
    __syncthreads();
    {
      float kv = 0.f, pv = 0.f;
      #pragma unroll
      for (int w=0; w<8; ++w){ kv += kq[w][tid]; pv += kpq[w][tid]; }
      att_vec[bt*512 + tid] = kv;
      kps[tid] = pv;
    }
    __syncthreads();
    {
      int q = tid & 3, hh = tid >> 2;
      #pragma unroll
      for (int p = 0; p < 4; ++p) {
        int h = p*128 + hh;
        const float* wr = cpW + (size_t)h*512 + q*128;
        const float* cr = c1s + q*128;
        float acc = 0.f;
        #pragma unroll
        for (int j = 0; j < 32; ++j) {
          float4 w4 = *(const float4*)(wr + j*4);
          float4 c4 = *(const float4*)(cr + j*4);
          acc += w4.x*c4.x + w4.y*c4.y + w4.z*c4.z + w4.w*c4.w;
        }
        acc += __shfl_xor(acc,1);
        acc += __shfl_xor(acc,2);
        if (q == 0) {
          float u = acc + kps[h] + bsum[h];
          float h1n = u * O1[bt*512 + h];
          h1s[h] = h1n;
          A2[bt*512 + h] = (_Float16)h1n;
        }
      }
    }
    __syncthreads();
  }
}

// ---------------------------------------------------------------------------
extern "C" void kernel_launch(void* const* d_in, const int* in_sizes, int n_in,
                              void* d_out, int out_size, void* d_ws, size_t ws_size,
                              hipStream_t stream) {
  const float* trg  = (const float*)d_in[0];
  const float* enc  = (const float*)d_in[1];
  const float* ehid = (const float*)d_in[2];
  const float* zW0 = (const float*)d_in[5];  const float* zb0 = (const float*)d_in[6];
  const float* fW0 = (const float*)d_in[7];  const float* fb0 = (const float*)d_in[8];
  const float* oW0 = (const float*)d_in[9];  const float* ob0 = (const float*)d_in[10];
  const float* iW0 = (const float*)d_in[11]; const float* ib0 = (const float*)d_in[12];
  const float* epzW0 = (const float*)d_in[13]; const float* epzb0 = (const float*)d_in[14];
  const float* epoW0 = (const float*)d_in[15]; const float* epob0 = (const float*)d_in[16];
  const float* epiW0 = (const float*)d_in[17]; const float* epib0 = (const float*)d_in[18];
  const float* zW1 = (const float*)d_in[19]; const float* zb1 = (const float*)d_in[20];
  const float* fW1 = (const float*)d_in[21]; const float* fb1 = (const float*)d_in[22];
  const float* oW1 = (const float*)d_in[23]; const float* ob1 = (const float*)d_in[24];
  const float* epzW1 = (const float*)d_in[25]; const float* epzb1 = (const float*)d_in[26];
  const float* epoW1 = (const float*)d_in[27]; const float* epob1 = (const float*)d_in[28];
  const float* kpW = (const float*)d_in[29]; const float* kpb = (const float*)d_in[30];
  const float* cpW = (const float*)d_in[31]; const float* cpb = (const float*)d_in[32];
  const float* outW = (const float*)d_in[33];

  float* out = (float*)d_out;
  float* att_probs = out + (size_t)65536000;            // B*T*V
  float* att_vec   = att_probs + (size_t)262144;        // + B*T*S

  // SMALL (persists past transient phases) in ws; BIG transients in ws if it
  // fits, else inside d_out's logits region (fully overwritten at the end).
  const size_t SMALL = 2097152 + 327680 + 65536 + 16384 + 2048;
  const size_t BIG   = 91226112;
  char* pA2  = (char*)d_ws;
  char* pep  = pA2  + 2097152;
  char* pc1  = pep  + 327680;
  char* psg  = pc1  + 65536;
  char* pcnt = psg  + 16384;
  char* big = (ws_size >= SMALL + BIG) ? pcnt + 2048 : (char*)d_out;
  char* p = big;
  _Float16* A0h  = (_Float16*)p; p += 4194304;
  _Float16* A0l  = (_Float16*)p; p += 4194304;
  _Float16* W0h  = (_Float16*)p; p += 4194304;
  _Float16* W0l  = (_Float16*)p; p += 4194304;
  _Float16* A1h  = (_Float16*)p; p += 4194304;
  _Float16* A1l  = (_Float16*)p; p += 4194304;
  _Float16* W1h  = (_Float16*)p; p += 3145728;
  _Float16* W1l  = (_Float16*)p; p += 3145728;
  _Float16* ench = (_Float16*)p; p += 4194304;
  _Float16* encl = (_Float16*)p; p += 4194304;
  _Float16* kph  = (_Float16*)p; p += 524288;
  _Float16* kpl  = (_Float16*)p; p += 524288;
  float*    C0   = (float*)p;    p += 16777216;
  float*    C1   = (float*)p;    p += 12582912;
  float*    F1   = (float*)p;    p += 4194304;
  float*    O1   = (float*)p;    p += 4194304;
  float*    PZ   = (float*)p;    p += 4194304;
  float*    EP   = (float*)p;    p += 8388608;
  _Float16* A2  = (_Float16*)pA2;
  float*    ep  = (float*)pep;
  float*    c1g = (float*)pc1;
  float*    sg  = (float*)psg;
  int*      cnt = (int*)pcnt;

  hipLaunchKernelGGL(ep_proj, dim3(1280), dim3(256), 0, stream,
      ehid, epzW0,epzb0, epoW0,epob0, epiW0,epib0, epzW1,epzb1, epoW1,epob1, ep);
  hipLaunchKernelGGL(pack2, dim3(31744), dim3(256), 0, stream,
      trg, zW0,fW0,oW0,iW0, zW1,fW1,oW1, enc, kpW,
      A0h,A0l, W0h,W0l, W1h,W1l, ench,encl, kph,kpl);
  hipLaunchKernelGGL(gemm3, dim3(16,16), dim3(256), 0, stream,
      A0h, A0l, W0h, W0l, C0, 1024, 2048);
  hipLaunchKernelGGL(scan0, dim3(64), dim3(256), 0, stream,
      C0, ep, zb0,fb0,ob0,ib0, A1h, A1l);
  hipLaunchKernelGGL(gemm3, dim3(16,12), dim3(256), 0, stream,
      A1h, A1l, W1h, W1l, C1, 1024, 1536);
  hipLaunchKernelGGL(act1, dim3(4096), dim3(256), 0, stream,
      C1, ep, zb1,fb1,ob1, F1, O1, PZ);
  hipLaunchKernelGGL(gemm3, dim3(32,4), dim3(256), 0, stream,
      ench, encl, kph, kpl, EP, 512, 512);

  hipLaunchKernelGGL(zinit, dim3(1), dim3(512), 0, stream, cnt);
  {
    const float *a0=enc, *a1=F1, *a2=O1, *a3=PZ, *a4=EP, *a5=cpW, *a6=kpb, *a7=cpb;
    float *a8=att_probs, *a9=att_vec; _Float16* a10=A2;
    float *a11=c1g, *a12=sg; int* a13=cnt;
    void* args[] = {&a0,&a1,&a2,&a3,&a4,&a5,&a6,&a7,&a8,&a9,&a10,&a11,&a12,&a13};
    hipError_t e = hipLaunchCooperativeKernel((const void*)decode_coop,
        dim3(256), dim3(512), args, 0, stream);
    if (e != hipSuccess)
      hipLaunchKernelGGL(decode, dim3(32), dim3(512), 0, stream,
          enc, F1, O1, PZ, EP, cpW, kpb, cpb, att_probs, att_vec, A2);
  }
  hipLaunchKernelGGL(gemm_hf, dim3(16,250), dim3(256), 0, stream,
      A2, outW, out, 512, 32000);
}

// Round 6
// 3024.258 us; speedup vs baseline: 3.0018x; 3.0018x over previous
//
#include <hip/hip_runtime.h>
#include <cmath>

// ---------------------------------------------------------------------------
// QRNN decoder, MI355X. B=32 T=64 S=128 EMB=H=E=512 V=32000 K=2.
// f32-faithful pipeline (sharp softmax -> argmax flips if any fp16 error
// reaches the score path). Split-fp16 (hi+lo) 3-term MFMA GEMMs for gates
// and EP = enc @ kpW^T; decode recurrence f32-faithful; vocab GEMM fp16.
// Decode: 32 blocks (1 per batch), enc fp16-hi LDS-resident (swizzled),
// scores = (LDS hi + streamed lo)*c1 in f32; EP/cpW streamed from L2
// (per-XCD working set ~2.5 MB < 4 MB L2). NO cross-block sync (round-5
// post-mortem: device-scope barriers cost ~68 us each on non-coherent XCDs).
// ---------------------------------------------------------------------------

typedef _Float16 half8  __attribute__((ext_vector_type(8)));
typedef float    f32x4  __attribute__((ext_vector_type(4)));

#define DEVFN static __device__ __forceinline__

DEVFN float sigp(float x){ return 1.f/(1.f+expf(-x)); }

DEVFN void glds16(const _Float16* g, _Float16* l){
  __builtin_amdgcn_global_load_lds((const __attribute__((address_space(1))) void*)g,
                                   (__attribute__((address_space(3))) void*)l, 16, 0, 0);
}

// ---------------- encoder-hidden projections: 5 x (B,E)@(E,H), f32 ---------
__global__ void ep_proj(const float* __restrict__ ehid,
    const float* __restrict__ w0, const float* __restrict__ b0,
    const float* __restrict__ w1, const float* __restrict__ b1,
    const float* __restrict__ w2, const float* __restrict__ b2,
    const float* __restrict__ w3, const float* __restrict__ b3,
    const float* __restrict__ w4, const float* __restrict__ b4,
    float* __restrict__ ep)
{
  int gid = blockIdx.x*256 + threadIdx.x;            // 5*32*512*4 = 327680
  int q = gid & 3, h = (gid>>2)&511, b = (gid>>11)&31, p = gid>>16;
  const float* w    = (p==0)?w0:(p==1)?w1:(p==2)?w2:(p==3)?w3:w4;
  const float* bias = (p==0)?b0:(p==1)?b1:(p==2)?b2:(p==3)?b3:b4;
  const float* x  = ehid + ((p>=3)?32*512:0) + b*512 + q*128;
  const float* wr = w + (size_t)h*512 + q*128;
  float acc = 0.f;
  #pragma unroll 8
  for (int j=0;j<128;j+=4){
    float4 wv = *(const float4*)(wr+j);
    float4 xv = *(const float4*)(x+j);
    acc += wv.x*xv.x + wv.y*xv.y + wv.z*xv.z + wv.w*xv.w;
  }
  acc += __shfl_xor(acc,1); acc += __shfl_xor(acc,2);
  if (q==0) ep[p*16384 + b*512 + h] = acc + bias[h];
}

// ---------------- hi/lo fp16 packing ---------------------------------------
__global__ void pack2(const float* __restrict__ trg,
  const float* __restrict__ zW0, const float* __restrict__ fW0,
  const float* __restrict__ oW0, const float* __restrict__ iW0,
  const float* __restrict__ zW1, const float* __restrict__ fW1,
  const float* __restrict__ oW1,
  const float* __restrict__ enc, const float* __restrict__ kpW,
  _Float16* __restrict__ A0h, _Float16* __restrict__ A0l,
  _Float16* __restrict__ W0h, _Float16* __restrict__ W0l,
  _Float16* __restrict__ W1h, _Float16* __restrict__ W1l,
  _Float16* __restrict__ ench, _Float16* __restrict__ encl,
  _Float16* __restrict__ kph, _Float16* __restrict__ kpl)
{
  int gid = blockIdx.x*256 + threadIdx.x;            // 8,126,464 total
  float v; _Float16 *ph, *pl; int idx;
  if (gid < 2097152) {
    idx = gid;
    int m = idx >> 10, c = idx & 1023, t = m & 63, kk = c >> 9, i = c & 511;
    v = (kk==0) ? ((t>0) ? trg[(size_t)(m-1)*512 + i] : 0.f)
                : trg[(size_t)m*512 + i];
    ph = A0h; pl = A0l;
  } else if (gid < 4194304) {
    idx = gid - 2097152;
    int r = idx >> 10, c = idx & 1023, g = r >> 9, o = r & 511, kk = c >> 9, i = c & 511;
    const float* W = (g==0)?zW0:(g==1)?fW0:(g==2)?oW0:iW0;
    v = W[(size_t)o*1024 + i*2 + kk];
    ph = W0h; pl = W0l;
  } else if (gid < 5767168) {
    idx = gid - 4194304;
    int r = idx >> 10, c = idx & 1023, g = r >> 9, o = r & 511, kk = c >> 9, i = c & 511;
    const float* W = (g==0)?zW1:(g==1)?fW1:oW1;
    v = W[(size_t)o*1024 + i*2 + kk];
    ph = W1h; pl = W1l;
  } else if (gid < 7864320) {
    idx = gid - 5767168;
    v = enc[idx];
    ph = ench; pl = encl;
  } else {
    idx = gid - 7864320;
    v = kpW[idx];
    ph = kph; pl = kpl;
  }
  _Float16 hi = (_Float16)v;
  _Float16 lo = (_Float16)(v - (float)hi);
  ph[idx] = hi; pl[idx] = lo;
}

// ---------------- split-fp16 3-term MFMA GEMM ------------------------------
__global__ __launch_bounds__(256) void gemm3(
    const _Float16* __restrict__ Ah, const _Float16* __restrict__ Al,
    const _Float16* __restrict__ Bh, const _Float16* __restrict__ Bl,
    float* __restrict__ C, int Kd, int ldc)
{
  __shared__ __align__(16) _Float16 Ahs[4096];
  __shared__ __align__(16) _Float16 Als[4096];
  __shared__ __align__(16) _Float16 Bhs[4096];
  __shared__ __align__(16) _Float16 Bls[4096];
  const int tid = threadIdx.x, lane = tid & 63, wave = tid >> 6;
  const int bm = blockIdx.x, bn = blockIdx.y;
  const int wm = wave >> 1, wn = wave & 1;
  const size_t aoff = ((size_t)bm*128 + wave*16 + (lane>>2))*Kd + (lane&3)*8;
  const size_t boff = ((size_t)bn*128 + wave*16 + (lane>>2))*Kd + (lane&3)*8;
  const size_t hstep = (size_t)64*Kd;
  _Float16* Ahl = Ahs + wave*512;
  _Float16* All = Als + wave*512;
  _Float16* Bhl = Bhs + wave*512;
  _Float16* Bll = Bls + wave*512;
  f32x4 acc[4][4] = {};
  for (int k0 = 0; k0 < Kd; k0 += 32) {
    glds16(Ah + aoff + k0, Ahl);  glds16(Ah + aoff + hstep + k0, Ahl + 2048);
    glds16(Al + aoff + k0, All);  glds16(Al + aoff + hstep + k0, All + 2048);
    glds16(Bh + boff + k0, Bhl);  glds16(Bh + boff + hstep + k0, Bhl + 2048);
    glds16(Bl + boff + k0, Bll);  glds16(Bl + boff + hstep + k0, Bll + 2048);
    __syncthreads();
    const int ar = lane & 15, kb = (lane>>4)*8;
    half8 ah[4], al[4], bh[4], bl[4];
    #pragma unroll
    for (int m=0;m<4;++m){
      ah[m] = *(const half8*)&Ahs[(wm*64 + m*16 + ar)*32 + kb];
      al[m] = *(const half8*)&Als[(wm*64 + m*16 + ar)*32 + kb];
    }
    #pragma unroll
    for (int n=0;n<4;++n){
      bh[n] = *(const half8*)&Bhs[(wn*64 + n*16 + ar)*32 + kb];
      bl[n] = *(const half8*)&Bls[(wn*64 + n*16 + ar)*32 + kb];
    }
    #pragma unroll
    for (int m=0;m<4;++m)
      #pragma unroll
      for (int n=0;n<4;++n){
        acc[m][n] = __builtin_amdgcn_mfma_f32_16x16x32_f16(ah[m], bh[n], acc[m][n], 0,0,0);
        acc[m][n] = __builtin_amdgcn_mfma_f32_16x16x32_f16(ah[m], bl[n], acc[m][n], 0,0,0);
        acc[m][n] = __builtin_amdgcn_mfma_f32_16x16x32_f16(al[m], bh[n], acc[m][n], 0,0,0);
      }
    __syncthreads();
  }
  const int r0 = bm*128 + wm*64 + ((lane>>4)<<2);
  const int c0 = bn*128 + wn*64 + (lane&15);
  #pragma unroll
  for (int m=0;m<4;++m)
    #pragma unroll
    for (int n=0;n<4;++n)
      #pragma unroll
      for (int e=0;e<4;++e)
        C[(size_t)(r0 + m*16 + e)*ldc + c0 + n*16] = acc[m][n][e];
}

// ---------------- vocab GEMM: plain fp16 A x f32->fp16 B -------------------
__global__ __launch_bounds__(256) void gemm_hf(
    const _Float16* __restrict__ A, const float* __restrict__ Bf,
    float* __restrict__ C, int Kd, int ldc)
{
  __shared__ __align__(16) _Float16 As[128*32];
  __shared__ __align__(16) _Float16 Bs[128*32];
  const int tid = threadIdx.x, lane = tid & 63, wave = tid >> 6;
  const int bm = blockIdx.x, bn = blockIdx.y;
  const int wm = wave >> 1, wn = wave & 1;
  const _Float16* Ag = A + ((size_t)bm*128 + wave*16 + (lane>>2))*Kd + (lane&3)*8;
  _Float16* Al = As + wave*512;
  const float* Bg = Bf + ((size_t)bn*128 + (tid>>2))*Kd + (tid&3)*8;
  f32x4 acc[4][4] = {};
  for (int k0 = 0; k0 < Kd; k0 += 32) {
    glds16(Ag + k0, Al);
    glds16(Ag + (size_t)64*Kd + k0, Al + 2048);
    #pragma unroll
    for (int i=0;i<2;++i){
      const float* src = Bg + (size_t)i*64*Kd + k0;
      float4 f0 = *(const float4*)src;
      float4 f1 = *(const float4*)(src+4);
      half8 hv = {(_Float16)f0.x,(_Float16)f0.y,(_Float16)f0.z,(_Float16)f0.w,
                  (_Float16)f1.x,(_Float16)f1.y,(_Float16)f1.z,(_Float16)f1.w};
      *(half8*)&Bs[i*2048 + tid*8] = hv;
    }
    __syncthreads();
    half8 af[4], bf[4];
    const int ar = lane & 15, kb = (lane>>4)*8;
    #pragma unroll
    for (int m=0;m<4;++m) af[m] = *(const half8*)&As[(wm*64 + m*16 + ar)*32 + kb];
    #pragma unroll
    for (int n=0;n<4;++n) bf[n] = *(const half8*)&Bs[(wn*64 + n*16 + ar)*32 + kb];
    #pragma unroll
    for (int m=0;m<4;++m)
      #pragma unroll
      for (int n=0;n<4;++n)
        acc[m][n] = __builtin_amdgcn_mfma_f32_16x16x32_f16(af[m], bf[n], acc[m][n], 0,0,0);
    __syncthreads();
  }
  const int r0 = bm*128 + wm*64 + ((lane>>4)<<2);
  const int c0 = bn*128 + wn*64 + (lane&15);
  #pragma unroll
  for (int m=0;m<4;++m)
    #pragma unroll
    for (int n=0;n<4;++n)
      #pragma unroll
      for (int e=0;e<4;++e)
        C[(size_t)(r0 + m*16 + e)*ldc + c0 + n*16] = acc[m][n][e];
}

// ---------------- layer-0 scan: f32, writes A1 hi/lo -----------------------
__global__ void scan0(const float* __restrict__ C0, const float* __restrict__ ep,
    const float* __restrict__ zb0, const float* __restrict__ fb0,
    const float* __restrict__ ob0, const float* __restrict__ ib0,
    _Float16* __restrict__ A1h, _Float16* __restrict__ A1l)
{
  int gid = blockIdx.x*256 + threadIdx.x;   // 16384
  int h = gid & 511, b = gid >> 9;
  float ez = ep[b*512 + h];
  float eo = ep[16384 + b*512 + h];
  float ei = ep[32768 + b*512 + h];
  float bz = zb0[h], bff = fb0[h], bo = ob0[h], bi = ib0[h];
  float c = 0.f;
  size_t base = (size_t)b*64*1024;
  A1h[base + h] = (_Float16)0.f;
  A1l[base + h] = (_Float16)0.f;
  for (int t=0;t<64;++t){
    size_t row = (size_t)b*64 + t;
    const float* g = C0 + row*2048;
    float z = tanhf(g[h]      + bz  + ez);
    float f = sigp (g[512+h]  + bff + ez);   // f0 uses epz0 (per reference)
    float o = sigp (g[1024+h] + bo  + eo);
    float i = sigp (g[1536+h] + bi  + ei);
    c = f*c + i*z;
    float h0 = o*c;
    _Float16 hi = (_Float16)h0;
    _Float16 lo = (_Float16)(h0 - (float)hi);
    A1h[row*1024 + 512 + h] = hi;
    A1l[row*1024 + 512 + h] = lo;
    if (t < 63){
      A1h[(row+1)*1024 + h] = hi;
      A1l[(row+1)*1024 + h] = lo;
    }
  }
}

// ---------------- layer-1 activations: F1, O1, PZ=(1-f1)*z1 ----------------
__global__ void act1(const float* __restrict__ C1, const float* __restrict__ ep,
    const float* __restrict__ zb1, const float* __restrict__ fb1,
    const float* __restrict__ ob1,
    float* __restrict__ F1, float* __restrict__ O1, float* __restrict__ PZ)
{
  int gid = blockIdx.x*256 + threadIdx.x;   // 2048*512
  int h = gid & 511; size_t row = gid >> 9; int b = (int)(row >> 6);
  const float* g = C1 + row*1536;
  float ez = ep[3*16384 + b*512 + h];
  float eo = ep[4*16384 + b*512 + h];
  float z1 = tanhf(g[h]      + zb1[h] + ez);
  float f1 = sigp (g[512+h]  + fb1[h] + ez);   // f1 uses epz1 (per reference)
  float o1 = sigp (g[1024+h] + ob1[h] + eo);
  F1[gid] = f1; O1[gid] = o1; PZ[gid] = (1.f - f1)*z1;
}

// ---------------- decode2: 32 blocks (1/b), enc-hi in LDS ------------------
// LDS: ench[128][512] fp16 swizzled (byte ^= (s&7)<<4) 128KB + kpq 16KB + small.
__global__ __launch_bounds__(512,1) void decode2(
  const _Float16* __restrict__ ench_g, const _Float16* __restrict__ encl_g,
  const float* __restrict__ F1, const float* __restrict__ O1,
  const float* __restrict__ PZ, const float* __restrict__ EP,
  const float* __restrict__ cpW, const float* __restrict__ kpb,
  const float* __restrict__ cpb,
  float* __restrict__ att_probs, float* __restrict__ att_vec,
  _Float16* __restrict__ A2)
{
  __shared__ __align__(16) unsigned char encs[131072];
  __shared__ float kpq[8][512];
  __shared__ float c1s[512], h1s[512], gv[512], bsum[512];
  __shared__ float scores[128], alpha[128];
  const int b = blockIdx.x, tid = threadIdx.x;
  const _Float16* enchb = ench_g + (size_t)b*65536;
  const _Float16* enclb = encl_g + (size_t)b*65536;
  const float*    EPb   = EP     + (size_t)b*65536;

  // preload enc-hi into LDS, swizzled (16B chunks; swz flips bit4 -> 16B-safe)
  for (int idx = tid; idx < 8192; idx += 512) {
    int s = idx >> 6, c = idx & 63;
    half8 v = *(const half8*)(enchb + (size_t)s*512 + c*8);
    int byte = (s*1024 + c*16) ^ ((s&7)<<4);
    *(half8*)(encs + byte) = v;
  }
  h1s[tid] = 0.f;
  bsum[tid] = kpb[tid] + cpb[tid];
  __syncthreads();

  for (int t = 0; t < 64; ++t) {
    const size_t bt = (size_t)b*64 + t;
    // phase 1: c1n = f1*h1 + (1-f1)*z1
    c1s[tid] = F1[bt*512 + tid]*h1s[tid] + PZ[bt*512 + tid];
    __syncthreads();
    // phase 2: scores[s] = (ench_LDS + encl_L2) . c1  (f32-faithful)
    {
      int s = tid >> 2, q = tid & 3;
      const _Float16* el = enclb + (size_t)s*512 + q*128;
      float acc = 0.f;
      #pragma unroll
      for (int j = 0; j < 16; ++j) {
        int byte = (s*1024 + (q*128 + j*8)*2) ^ ((s&7)<<4);
        half8 eh  = *(const half8*)(encs + byte);
        half8 elv = *(const half8*)(el + j*8);
        const float* cr = c1s + q*128 + j*8;
        #pragma unroll
        for (int u = 0; u < 8; ++u)
          acc += ((float)eh[u] + (float)elv[u]) * cr[u];
      }
      acc += __shfl_xor(acc,1); acc += __shfl_xor(acc,2);
      if (q == 0) scores[s] = acc;
    }
    __syncthreads();
    // phase 3: softmax (wave 0)
    if (tid < 64) {
      float s0 = scores[tid], s1 = scores[tid+64];
      float m = fmaxf(s0, s1);
      #pragma unroll
      for (int off=32; off; off>>=1) m = fmaxf(m, __shfl_xor(m, off));
      float e0 = expf(s0-m), e1 = expf(s1-m);
      float sm = e0+e1;
      #pragma unroll
      for (int off=32; off; off>>=1) sm += __shfl_xor(sm, off);
      float inv = 1.f/sm;
      float a0 = e0*inv, a1 = e1*inv;
      alpha[tid] = a0; alpha[tid+64] = a1;
      att_probs[bt*128 + tid] = a0; att_probs[bt*128 + 64 + tid] = a1;
    }
    __syncthreads();
    // phase 4 (three independent streams, TLP across 8 waves):
    // 4a: gv[h] = c1n . cpW[h,:]   (1 MB L2 stream, shared across b's on XCD)
    {
      int q = tid & 3, hh = tid >> 2;
      #pragma unroll
      for (int p = 0; p < 4; ++p) {
        int h = p*128 + hh;
        const float* wr = cpW + (size_t)h*512 + q*128;
        const float* cr = c1s + q*128;
        float acc = 0.f;
        #pragma unroll 8
        for (int j = 0; j < 32; ++j) {
          float4 w4 = *(const float4*)(wr + j*4);
          float4 c4 = *(const float4*)(cr + j*4);
          acc += w4.x*c4.x + w4.y*c4.y + w4.z*c4.z + w4.w*c4.w;
        }
        acc += __shfl_xor(acc,1); acc += __shfl_xor(acc,2);
        if (q == 0) gv[h] = acc;
      }
    }
    // 4b: kp partials = alpha . EP  (256 KB L2 stream, coalesced by wave)
    {
      int w = tid >> 6, l = tid & 63;
      const float* pr = EPb + (size_t)(w*16)*512 + l*8;
      float p0=0,p1=0,p2=0,p3=0,p4=0,p5=0,p6=0,p7=0;
      #pragma unroll
      for (int si = 0; si < 16; ++si) {
        float a = alpha[w*16 + si];
        float4 q0 = *(const float4*)(pr + si*512);
        float4 q1 = *(const float4*)(pr + si*512 + 4);
        p0 += a*q0.x; p1 += a*q0.y; p2 += a*q0.z; p3 += a*q0.w;
        p4 += a*q1.x; p5 += a*q1.y; p6 += a*q1.z; p7 += a*q1.w;
      }
      *(float4*)&kpq[w][l*8]   = make_float4(p0,p1,p2,p3);
      *(float4*)&kpq[w][l*8+4] = make_float4(p4,p5,p6,p7);
    }
    // 4c: k[h] = alpha . enc[:,h] from LDS hi (fp16 ok for att_vec)
    {
      float kv = 0.f;
      int col2 = tid*2;
      #pragma unroll 8
      for (int s = 0; s < 128; ++s) {
        int byte = (s*1024 + col2) ^ ((s&7)<<4);
        _Float16 e = *(const _Float16*)(encs + byte);
        kv += alpha[s] * (float)e;
      }
      att_vec[bt*512 + tid] = kv;
    }
    __syncthreads();
    // phase 5: combine -> h1n
    {
      float kp = 0.f;
      #pragma unroll
      for (int w = 0; w < 8; ++w) kp += kpq[w][tid];
      float h1n = (kp + gv[tid] + bsum[tid]) * O1[bt*512 + tid];
      h1s[tid] = h1n;
      A2[bt*512 + tid] = (_Float16)h1n;
    }
    __syncthreads();
  }
}

// ---------------------------------------------------------------------------
extern "C" void kernel_launch(void* const* d_in, const int* in_sizes, int n_in,
                              void* d_out, int out_size, void* d_ws, size_t ws_size,
                              hipStream_t stream) {
  const float* trg  = (const float*)d_in[0];
  const float* enc  = (const float*)d_in[1];
  const float* ehid = (const float*)d_in[2];
  const float* zW0 = (const float*)d_in[5];  const float* zb0 = (const float*)d_in[6];
  const float* fW0 = (const float*)d_in[7];  const float* fb0 = (const float*)d_in[8];
  const float* oW0 = (const float*)d_in[9];  const float* ob0 = (const float*)d_in[10];
  const float* iW0 = (const float*)d_in[11]; const float* ib0 = (const float*)d_in[12];
  const float* epzW0 = (const float*)d_in[13]; const float* epzb0 = (const float*)d_in[14];
  const float* epoW0 = (const float*)d_in[15]; const float* epob0 = (const float*)d_in[16];
  const float* epiW0 = (const float*)d_in[17]; const float* epib0 = (const float*)d_in[18];
  const float* zW1 = (const float*)d_in[19]; const float* zb1 = (const float*)d_in[20];
  const float* fW1 = (const float*)d_in[21]; const float* fb1 = (const float*)d_in[22];
  const float* oW1 = (const float*)d_in[23]; const float* ob1 = (const float*)d_in[24];
  const float* epzW1 = (const float*)d_in[25]; const float* epzb1 = (const float*)d_in[26];
  const float* epoW1 = (const float*)d_in[27]; const float* epob1 = (const float*)d_in[28];
  const float* kpW = (const float*)d_in[29]; const float* kpb = (const float*)d_in[30];
  const float* cpW = (const float*)d_in[31]; const float* cpb = (const float*)d_in[32];
  const float* outW = (const float*)d_in[33];

  float* out = (float*)d_out;
  float* att_probs = out + (size_t)65536000;            // B*T*V
  float* att_vec   = att_probs + (size_t)262144;        // + B*T*S

  // SMALL (persists) in ws; BIG transients in ws if it fits, else inside
  // d_out's logits region (fully overwritten by the final GEMM).
  const size_t SMALL = 2097152 + 327680;
  const size_t BIG   = 91226112;
  char* pA2  = (char*)d_ws;
  char* pep  = pA2  + 2097152;
  char* big = (ws_size >= SMALL + BIG) ? pep + 327680 : (char*)d_out;
  char* p = big;
  _Float16* A0h  = (_Float16*)p; p += 4194304;
  _Float16* A0l  = (_Float16*)p; p += 4194304;
  _Float16* W0h  = (_Float16*)p; p += 4194304;
  _Float16* W0l  = (_Float16*)p; p += 4194304;
  _Float16* A1h  = (_Float16*)p; p += 4194304;
  _Float16* A1l  = (_Float16*)p; p += 4194304;
  _Float16* W1h  = (_Float16*)p; p += 3145728;
  _Float16* W1l  = (_Float16*)p; p += 3145728;
  _Float16* ench = (_Float16*)p; p += 4194304;
  _Float16* encl = (_Float16*)p; p += 4194304;
  _Float16* kph  = (_Float16*)p; p += 524288;
  _Float16* kpl  = (_Float16*)p; p += 524288;
  float*    C0   = (float*)p;    p += 16777216;
  float*    C1   = (float*)p;    p += 12582912;
  float*    F1   = (float*)p;    p += 4194304;
  float*    O1   = (float*)p;    p += 4194304;
  float*    PZ   = (float*)p;    p += 4194304;
  float*    EP   = (float*)p;    p += 8388608;
  _Float16* A2  = (_Float16*)pA2;
  float*    ep  = (float*)pep;

  hipLaunchKernelGGL(ep_proj, dim3(1280), dim3(256), 0, stream,
      ehid, epzW0,epzb0, epoW0,epob0, epiW0,epib0, epzW1,epzb1, epoW1,epob1, ep);
  hipLaunchKernelGGL(pack2, dim3(31744), dim3(256), 0, stream,
      trg, zW0,fW0,oW0,iW0, zW1,fW1,oW1, enc, kpW,
      A0h,A0l, W0h,W0l, W1h,W1l, ench,encl, kph,kpl);
  hipLaunchKernelGGL(gemm3, dim3(16,16), dim3(256), 0, stream,
      A0h, A0l, W0h, W0l, C0, 1024, 2048);
  hipLaunchKernelGGL(scan0, dim3(64), dim3(256), 0, stream,
      C0, ep, zb0,fb0,ob0,ib0, A1h, A1l);
  hipLaunchKernelGGL(gemm3, dim3(16,12), dim3(256), 0, stream,
      A1h, A1l, W1h, W1l, C1, 1024, 1536);
  hipLaunchKernelGGL(act1, dim3(4096), dim3(256), 0, stream,
      C1, ep, zb1,fb1,ob1, F1, O1, PZ);
  hipLaunchKernelGGL(gemm3, dim3(32,4), dim3(256), 0, stream,
      ench, encl, kph, kpl, EP, 512, 512);
  hipLaunchKernelGGL(decode2, dim3(32), dim3(512), 0, stream,
      ench, encl, F1, O1, PZ, EP, cpW, kpb, cpb, att_probs, att_vec, A2);
  hipLaunchKernelGGL(gemm_hf, dim3(16,250), dim3(256), 0, stream,
      A2, outW, out, 512, 32000);
}